// Round 2
// baseline (17502.225 us; speedup 1.0000x reference)
//
#include <hip/hip_runtime.h>
#include <cstddef>

#define VV 32000
#define EOSI 31999
#define LOG_BOUND (-1.0005003335835335e-3f)  // log(0.999)

typedef float  floatx4  __attribute__((ext_vector_type(4)));
typedef short  bf16x8   __attribute__((ext_vector_type(8)));
typedef unsigned short ushortx8 __attribute__((ext_vector_type(8)));

__device__ __forceinline__ float softplusf(float x) {
  return fmaxf(x, 0.0f) + log1pf(expf(-fabsf(x)));
}
__device__ __forceinline__ float sigmoidf(float x) {
  return 1.0f / (1.0f + expf(-x));
}
__device__ __forceinline__ unsigned short f2bf(float f) {
  union { float f; unsigned u; } v; v.f = f;
  unsigned u = v.u;
  return (unsigned short)((u + 0x7fffu + ((u >> 16) & 1u)) >> 16);  // RNE
}

// Zero h slot 0 for both layers + barrier counters (ws poisoned 0xAA each call)
__global__ void init_misc(float* h0, float* h1, unsigned* bars) {
  int i = blockIdx.x * 256 + threadIdx.x;   // 16 blocks -> 4096 threads
  h0[i] = 0.f; h1[i] = 0.f;
  if (i < 8) bars[i] = 0u;
}

// ---------------------------------------------------------------------------
// bf16 MFMA GEMM: C[M,N] f32 = A(f32)[M,K] @ B(f32)[N,K]^T (+ bias1 + bias2)
// f32 inputs converted to bf16 (RNE) during LDS staging.
// mode 0: A row = m + arow_off
// mode 1: A row = tokens[((m&3)<<9) + (m>>2)]        (embedding gather, m=t*4+b)
// mode 2: A row = ((m&511)<<2) + (m>>9) + 4          (h buffer -> m=b*512+t)
// Tile 128x128, BK=32, 256 threads = 4 waves in 2x2, each wave 64x64 (4x4 MFMA).
// ---------------------------------------------------------------------------
__global__ __launch_bounds__(256) void mgemm(
    const float* __restrict__ A, const float* __restrict__ B, float* __restrict__ C,
    int M, int N, int K,
    const float* __restrict__ bias1, const float* __restrict__ bias2,
    const int* __restrict__ tokens, int mode, int arow_off)
{
  // row stride 40 ushort (80 B): 16B-aligned chunks, ~2-way LDS banking
  __shared__ unsigned short As[128 * 40];
  __shared__ unsigned short Bs[128 * 40];

  const int tid  = threadIdx.x;
  const int wave = tid >> 6, lane = tid & 63;
  const int ln15 = lane & 15, kq = lane >> 4;          // frag row / k-quad
  const int bcol = blockIdx.x * 128, brow = blockIdx.y * 128;
  const int wm = (wave >> 1) * 64, wn = (wave & 1) * 64;

  // staging: thread covers (row sr, 16 K-elements at offset sh)
  const int sr = tid >> 1, sh = (tid & 1) * 16;
  long arow;
  {
    int m = brow + sr;
    if (mode == 1)      arow = tokens[((m & 3) << 9) + (m >> 2)];
    else if (mode == 2) arow = ((m & 511) << 2) + (m >> 9) + 4;
    else                arow = m + arow_off;
  }
  const float* Ap = A + arow * (long)K + sh;
  const float* Bp = B + (long)(bcol + sr) * K + sh;

  floatx4 acc[4][4];
  #pragma unroll
  for (int i = 0; i < 4; ++i)
    #pragma unroll
    for (int j = 0; j < 4; ++j)
      acc[i][j] = (floatx4){0.f, 0.f, 0.f, 0.f};

  for (int k0 = 0; k0 < K; k0 += 32) {
    float4 a0 = *(const float4*)(Ap + k0 + 0);
    float4 a1 = *(const float4*)(Ap + k0 + 4);
    float4 a2 = *(const float4*)(Ap + k0 + 8);
    float4 a3 = *(const float4*)(Ap + k0 + 12);
    float4 b0 = *(const float4*)(Bp + k0 + 0);
    float4 b1 = *(const float4*)(Bp + k0 + 4);
    float4 b2 = *(const float4*)(Bp + k0 + 8);
    float4 b3 = *(const float4*)(Bp + k0 + 12);
    __syncthreads();
    {
      ushortx8 p0, p1;
      p0[0]=f2bf(a0.x); p0[1]=f2bf(a0.y); p0[2]=f2bf(a0.z); p0[3]=f2bf(a0.w);
      p0[4]=f2bf(a1.x); p0[5]=f2bf(a1.y); p0[6]=f2bf(a1.z); p0[7]=f2bf(a1.w);
      p1[0]=f2bf(a2.x); p1[1]=f2bf(a2.y); p1[2]=f2bf(a2.z); p1[3]=f2bf(a2.w);
      p1[4]=f2bf(a3.x); p1[5]=f2bf(a3.y); p1[6]=f2bf(a3.z); p1[7]=f2bf(a3.w);
      *(ushortx8*)&As[sr * 40 + sh]     = p0;
      *(ushortx8*)&As[sr * 40 + sh + 8] = p1;
      p0[0]=f2bf(b0.x); p0[1]=f2bf(b0.y); p0[2]=f2bf(b0.z); p0[3]=f2bf(b0.w);
      p0[4]=f2bf(b1.x); p0[5]=f2bf(b1.y); p0[6]=f2bf(b1.z); p0[7]=f2bf(b1.w);
      p1[0]=f2bf(b2.x); p1[1]=f2bf(b2.y); p1[2]=f2bf(b2.z); p1[3]=f2bf(b2.w);
      p1[4]=f2bf(b3.x); p1[5]=f2bf(b3.y); p1[6]=f2bf(b3.z); p1[7]=f2bf(b3.w);
      *(ushortx8*)&Bs[sr * 40 + sh]     = p0;
      *(ushortx8*)&Bs[sr * 40 + sh + 8] = p1;
    }
    __syncthreads();

    bf16x8 af[4], bfr[4];
    #pragma unroll
    for (int i = 0; i < 4; ++i)
      af[i] = *(const bf16x8*)&As[(wm + i * 16 + ln15) * 40 + kq * 8];
    #pragma unroll
    for (int j = 0; j < 4; ++j)
      bfr[j] = *(const bf16x8*)&Bs[(wn + j * 16 + ln15) * 40 + kq * 8];
    #pragma unroll
    for (int i = 0; i < 4; ++i)
      #pragma unroll
      for (int j = 0; j < 4; ++j)
        acc[i][j] = __builtin_amdgcn_mfma_f32_16x16x32_bf16(af[i], bfr[j], acc[i][j], 0, 0, 0);
  }

  // epilogue: C/D layout col = lane&15, row = (lane>>4)*4 + reg
  #pragma unroll
  for (int j = 0; j < 4; ++j) {
    int col = bcol + wn + j * 16 + ln15;
    float bb = bias1 ? (bias1[col] + bias2[col]) : 0.f;
    #pragma unroll
    for (int i = 0; i < 4; ++i) {
      int row0 = brow + wm + i * 16 + kq * 4;
      #pragma unroll
      for (int r = 0; r < 4; ++r)
        C[(size_t)(row0 + r) * N + col] = acc[i][j][r] + bb;
    }
  }
}

// ---------------------------------------------------------------------------
// Persistent LSTM layer: 512 timesteps in ONE launch.
// 256 blocks (1/CU guaranteed resident) x 256 threads; block bl owns h-dims
// [4bl,4bl+4) x 4 gates = 16 Whh rows. Whh slice lives in REGISTERS (64 VGPR
// per thread) - read from HBM exactly once. Software grid barrier per step
// (agent-scope release/acquire). c persists in registers of threads 0..15.
// ---------------------------------------------------------------------------
__global__ __launch_bounds__(256) void lstm_persist(
    const float* __restrict__ gpre,   // (512,4,4096): [(t*4+b)*4096 + gate*1024 + dim]
    const float* __restrict__ Whh,    // (4096,1024)
    float* __restrict__ hbuf,         // (513,4,1024); slot 0 zeroed
    unsigned* __restrict__ bar)       // zeroed counter
{
  __shared__ float hs[4096];
  __shared__ float part[16][17][4];   // [row][ks][b], padded
  __shared__ float gv[16][4];

  const int tid = threadIdx.x;
  const int bl  = blockIdx.x;
  const int row = tid >> 4, ks = tid & 15;             // 16 rows x 16 K-splits
  const int wrow = (row >> 2) * 1024 + bl * 4 + (row & 3);

  float4 wreg[16];
  {
    const float4* w4 = (const float4*)(Whh + (size_t)wrow * 1024);
    #pragma unroll
    for (int i = 0; i < 16; ++i) wreg[i] = w4[i * 16 + ks];
  }

  const int rb_r = tid >> 2, rb_b = tid & 3;           // reduce (tid<64)
  const int g_d  = tid >> 2, g_b  = tid & 3;           // gates  (tid<16)
  float creg = 0.f;

  for (int t = 0; t < 512; ++t) {
    float gp = 0.f;
    if (tid < 64)
      gp = gpre[(size_t)(t * 4 + rb_b) * 4096 + (rb_r >> 2) * 1024 + bl * 4 + (rb_r & 3)];

    // stage h_t into LDS
    {
      const float4* hp = (const float4*)(hbuf + (size_t)t * 4096);
      float4* hsv = (float4*)hs;
      #pragma unroll
      for (int i = 0; i < 4; ++i) hsv[tid + i * 256] = hp[tid + i * 256];
    }
    __syncthreads();

    // dot: 64 K-elements x 4 batches against register-resident Whh slice
    const float4* h4 = (const float4*)hs;
    float a0 = 0.f, a1 = 0.f, a2 = 0.f, a3 = 0.f;
    #pragma unroll
    for (int i = 0; i < 16; ++i) {
      int k4 = i * 16 + ks;
      float4 w  = wreg[i];
      float4 h0 = h4[k4];
      float4 h1 = h4[256 + k4];
      float4 h2 = h4[512 + k4];
      float4 h3 = h4[768 + k4];
      a0 += w.x*h0.x + w.y*h0.y + w.z*h0.z + w.w*h0.w;
      a1 += w.x*h1.x + w.y*h1.y + w.z*h1.z + w.w*h1.w;
      a2 += w.x*h2.x + w.y*h2.y + w.z*h2.z + w.w*h2.w;
      a3 += w.x*h3.x + w.y*h3.y + w.z*h3.z + w.w*h3.w;
    }
    *(float4*)&part[row][ks][0] = make_float4(a0, a1, a2, a3);
    __syncthreads();

    if (tid < 64) {
      float s = 0.f;
      #pragma unroll
      for (int k = 0; k < 16; ++k) s += part[rb_r][k][rb_b];
      gv[rb_r][rb_b] = gp + s;
    }
    __syncthreads();

    if (tid < 16) {
      float gi = gv[g_d][g_b], gf = gv[4 + g_d][g_b];
      float gg = gv[8 + g_d][g_b], go = gv[12 + g_d][g_b];
      float c = sigmoidf(gf) * creg + sigmoidf(gi) * tanhf(gg);
      creg = c;
      float h = sigmoidf(go) * tanhf(c);
      hbuf[(size_t)(t + 1) * 4096 + g_b * 1024 + bl * 4 + g_d] = h;
    }
    __syncthreads();

    if (t < 511) {
      if (tid == 0) {
        __threadfence();  // publish h writes (agent scope)
        __hip_atomic_fetch_add(bar, 1u, __ATOMIC_RELEASE, __HIP_MEMORY_SCOPE_AGENT);
        unsigned tgt = 256u * (unsigned)(t + 1);
        while (__hip_atomic_load(bar, __ATOMIC_ACQUIRE, __HIP_MEMORY_SCOPE_AGENT) < tgt) {
          __builtin_amdgcn_s_sleep(1);
        }
      }
      __syncthreads();
    }
  }
}

// ---------------------------------------------------------------------------
// Per-row stats over logits (see R0 derivation: full-row logsumexp collapses
// to logaddexp(shift, lprob_eos))
// ---------------------------------------------------------------------------
__global__ __launch_bounds__(256) void row_stats(
    const float* __restrict__ logits, float* __restrict__ rowA, float* __restrict__ rowE)
{
  const int m = blockIdx.x;
  const float* rowp = logits + (size_t)m * VV;
  __shared__ float red[8];
  const int tid = threadIdx.x;

  float mx = -3.0e38f;
  for (int v = tid; v < EOSI; v += 256) mx = fmaxf(mx, rowp[v]);
  for (int off = 32; off; off >>= 1) mx = fmaxf(mx, __shfl_down(mx, off, 64));
  if ((tid & 63) == 0) red[tid >> 6] = mx;
  __syncthreads();
  if (tid == 0) red[4] = fmaxf(fmaxf(red[0], red[1]), fmaxf(red[2], red[3]));
  __syncthreads();
  mx = red[4];

  float s = 0.f;
  for (int v = tid; v < EOSI; v += 256) s += expf(rowp[v] - mx);
  for (int off = 32; off; off >>= 1) s += __shfl_down(s, off, 64);
  if ((tid & 63) == 0) red[tid >> 6] = s;
  __syncthreads();

  if (tid == 0) {
    s = red[0] + red[1] + red[2] + red[3];
    float lse_v = mx + logf(s);
    float eos = rowp[EOSI];
    int t = m & 511;                         // m = b*512 + t
    float log_lb = (float)(t + 1) * LOG_BOUND;
    float log_eos_lb = -softplusf(eos);
    float log_eos_ub = -softplusf(-eos);
    float shift = log_lb + log_eos_lb;
    float f_lb = -expm1f(log_lb);
    float log_lb_eos = logf(f_lb) + log_eos_lb;
    float lprob_eos = log_lb_eos + softplusf(log_eos_ub - log_lb_eos);
    float aa = shift, bb = lprob_eos;
    float lse2 = fmaxf(aa, bb) + log1pf(expf(-fabsf(aa - bb)));
    rowA[m] = lse_v + lse2 - shift;
    rowE[m] = lprob_eos - lse2;
  }
}

__global__ __launch_bounds__(256) void finalize(
    float* __restrict__ out, const float* __restrict__ rowA, const float* __restrict__ rowE)
{
  const int m = blockIdx.y;
  const int v4 = blockIdx.x * 256 + threadIdx.x;   // 8000 float4 per row
  if (v4 >= 8000) return;
  float4* rp = (float4*)(out + (size_t)m * VV);
  const float Av = rowA[m];
  float4 p = rp[v4];
  p.x -= Av; p.y -= Av; p.z -= Av; p.w -= Av;
  if (v4 == 7999) p.w = rowE[m];
  rp[v4] = p;
}

extern "C" void kernel_launch(void* const* d_in, const int* in_sizes, int n_in,
                              void* d_out, int out_size, void* d_ws, size_t ws_size,
                              hipStream_t stream)
{
  const int*   tokens = (const int*)  d_in[0];
  const float* emb    = (const float*)d_in[1];
  const float* Wproj  = (const float*)d_in[2];
  const float* Wih0   = (const float*)d_in[3];
  const float* Whh0   = (const float*)d_in[4];
  const float* bih0   = (const float*)d_in[5];
  const float* bhh0   = (const float*)d_in[6];
  const float* Wih1   = (const float*)d_in[7];
  const float* Whh1   = (const float*)d_in[8];
  const float* bih1   = (const float*)d_in[9];
  const float* bhh1   = (const float*)d_in[10];
  float* out = (float*)d_out;

  // ws layout (floats): ~50.4 MB
  float* ws   = (float*)d_ws;
  float* g    = ws;                         // 2048*4096 (reused for both layers)
  float* h0   = g  + (size_t)2048 * 4096;   // 513*4096
  float* h1   = h0 + (size_t)513 * 4096;    // 513*4096
  float* rowA = h1 + (size_t)513 * 4096;    // 2048
  float* rowE = rowA + 2048;                // 2048
  unsigned* bars = (unsigned*)(rowE + 2048);

  init_misc<<<16, 256, 0, stream>>>(h0, h1, bars);

  // layer 0 input gates: emb[tokens] @ Wih0^T + bih0 + bhh0
  mgemm<<<dim3(32, 16), 256, 0, stream>>>(emb, Wih0, g, 2048, 4096, 1024,
                                          bih0, bhh0, tokens, 1, 0);
  lstm_persist<<<256, 256, 0, stream>>>(g, Whh0, h0, bars + 0);

  // layer 1 input gates: h0_all @ Wih1^T + bih1 + bhh1  (A row = m + 4)
  mgemm<<<dim3(32, 16), 256, 0, stream>>>(h0, Wih1, g, 2048, 4096, 1024,
                                          bih1, bhh1, nullptr, 0, 4);
  lstm_persist<<<256, 256, 0, stream>>>(g, Whh1, h1, bars + 1);

  // projection: logits into d_out, row m = b*512 + t
  mgemm<<<dim3(250, 16), 256, 0, stream>>>(h1, Wproj, out, 2048, 32000, 1024,
                                           nullptr, nullptr, nullptr, 2, 0);

  row_stats<<<2048, 256, 0, stream>>>(out, rowA, rowE);
  finalize<<<dim3(32, 2048), 256, 0, stream>>>(out, rowA, rowE);
}